// Round 1
// baseline (69.777 us; speedup 1.0000x reference)
//
#include <hip/hip_runtime.h>

// Shapes (compile-time, from reference):
//   x: (B=4, C=40, D=64, H=66, W=64) fp32
//   out0: (B=4, CC=160, D=64, HP=17, W=64) fp32 ; out1: scalar pad_1 = 2
// Mapping:
//   cc -> c=cc/4, p=cc%4, j=(cc/8)%5
//   out[b,cc,d,hp,w] = (0<=d+2-j<64) ? x[b, c, d+2-j, fold(hp*4+p), w] : 0
//   fold(h) = h>=66 ? h-66 : h   (circular H pad of 2)

constexpr int kB = 4, kC = 40, kD = 64, kH = 66, kW = 64;
constexpr int kHP = 17, kCC = 160;
constexpr long long kTotal = (long long)kB * kCC * kD * kHP * kW; // 44,564,480
constexpr int kNV = (int)(kTotal / 4);                            // 11,141,120 vec4

__global__ __launch_bounds__(256) void torch_shift_kernel(
    const float* __restrict__ in, float* __restrict__ out) {
  const int stride = gridDim.x * blockDim.x;
  for (int v = blockIdx.x * blockDim.x + threadIdx.x; v < kNV; v += stride) {
    const int wv  = v & 15;       // 16 vec4 per W-row (W=64)
    const int row = v >> 4;       // (b, cc, d, hp)
    const int hp  = row % kHP;
    const int t   = row / kHP;
    const int d   = t & 63;
    const int t2  = t >> 6;
    const int cc  = t2 % kCC;
    const int b   = t2 / kCC;

    const int j  = (cc >> 3) % 5;
    const int sd = d + 2 - j;

    float4 val = make_float4(0.f, 0.f, 0.f, 0.f);
    if ((unsigned)sd < (unsigned)kD) {
      const int c = cc >> 2;
      const int p = cc & 3;
      int h = hp * 4 + p;
      if (h >= kH) h -= kH;                 // circular fold (pad_1 = 2)
      const int src = (((b * kC + c) * kD + sd) * kH + h) * kW + (wv << 2);
      val = *reinterpret_cast<const float4*>(in + src);
    }
    *reinterpret_cast<float4*>(out + (long long)v * 4) = val;
  }
  if (blockIdx.x == 0 && threadIdx.x == 0) {
    out[kTotal] = 2.0f;  // pad_1, read back as float32 by the harness
  }
}

extern "C" void kernel_launch(void* const* d_in, const int* in_sizes, int n_in,
                              void* d_out, int out_size, void* d_ws, size_t ws_size,
                              hipStream_t stream) {
  const float* x = (const float*)d_in[0];
  float* out = (float*)d_out;
  const int blocks = 2048;
  torch_shift_kernel<<<blocks, 256, 0, stream>>>(x, out);
}

// Round 3
// 56.369 us; speedup vs baseline: 1.2379x; 1.2379x over previous
//
#include <hip/hip_runtime.h>

// Shapes (compile-time, from reference):
//   x: (B=4, C=40, D=64, H=66, W=64) fp32
//   out0: (B=4, CC=160, D=64, HP=17, W=64) fp32 ; out1: scalar pad_1 = 2
// Mapping:
//   cc -> c=cc/4, p=cc%4, j=(cc/8)%5
//   out[b,cc,d,hp,w] = (0<=d+2-j<64) ? x[b, c, d+2-j, fold(hp*4+p), w] : 0
//   fold(h) = h>=66 ? h-66 : h   (circular H pad of 2)

typedef float f32x4 __attribute__((ext_vector_type(4)));

constexpr int kB = 4, kC = 40, kD = 64, kH = 66, kW = 64;
constexpr int kHP = 17, kCC = 160;
constexpr long long kTotal = (long long)kB * kCC * kD * kHP * kW; // 44,564,480
constexpr int kNV = (int)(kTotal / 4);                            // 11,141,120 vec4
// kNV = 1024 * 10880 exactly; 2176 blocks * 5 iters * 1024 vec4 covers all.
constexpr int kBlocks = 2176;

__global__ __launch_bounds__(256) void torch_shift_kernel(
    const float* __restrict__ in, float* __restrict__ out) {
  const int chunk = kBlocks * 1024;
  for (int base = blockIdx.x * 1024 + threadIdx.x; base < kNV; base += chunk) {
    f32x4 vals[4];
#pragma unroll
    for (int k = 0; k < 4; ++k) {
      const int v  = base + k * 256;
      const int wv  = v & 15;       // 16 vec4 per W-row (W=64)
      const int row = v >> 4;       // (b, cc, d, hp)
      const int hp  = row % kHP;
      const int t   = row / kHP;
      const int d   = t & 63;
      const int t2  = t >> 6;
      const int cc  = t2 % kCC;
      const int b   = t2 / kCC;

      const int j  = (cc >> 3) % 5;
      const int sd = d + 2 - j;

      vals[k] = (f32x4){0.f, 0.f, 0.f, 0.f};
      if ((unsigned)sd < (unsigned)kD) {
        const int c = cc >> 2;
        const int p = cc & 3;
        int h = hp * 4 + p;
        if (h >= kH) h -= kH;               // circular fold (pad_1 = 2)
        const int src = (((b * kC + c) * kD + sd) * kH + h) * kW + (wv << 2);
        vals[k] = *reinterpret_cast<const f32x4*>(in + src);
      }
    }
#pragma unroll
    for (int k = 0; k < 4; ++k) {
      const int v = base + k * 256;
      __builtin_nontemporal_store(vals[k],
          reinterpret_cast<f32x4*>(out + (long long)v * 4));
    }
  }
  if (blockIdx.x == 0 && threadIdx.x == 0) {
    out[kTotal] = 2.0f;  // pad_1, read back as float32 by the harness
  }
}

extern "C" void kernel_launch(void* const* d_in, const int* in_sizes, int n_in,
                              void* d_out, int out_size, void* d_ws, size_t ws_size,
                              hipStream_t stream) {
  const float* x = (const float*)d_in[0];
  float* out = (float*)d_out;
  torch_shift_kernel<<<kBlocks, 256, 0, stream>>>(x, out);
}